// Round 2
// baseline (192.949 us; speedup 1.0000x reference)
//
#include <hip/hip_runtime.h>

#define NQ 16384
#define NB 128
#define NF 64
#define HD 128
#define EPSF 1e-8f

// ---------- helpers ----------
__device__ __forceinline__ float wave_allreduce_sum(float v) {
    // 64-lane wave on gfx950
    #pragma unroll
    for (int m = 1; m < 64; m <<= 1) v += __shfl_xor(v, m, 64);
    return v;
}

// ---------- kernel A: build (b,f) table ----------
// tableD[f*NB + b] = float4(-2*Pr, -2*Pi, Pr^2+Pi^2+eps, -softplus(qw[b,f]))
// tableM[f*NB + b] = mw[b,f]
// Layout is f-major so kernel B's lane=b register reload is coalesced.
__global__ __launch_bounds__(64) void build_table_kernel(
    const float* __restrict__ probes,   // [NB][HD]
    const float* __restrict__ angles,   // [NF]
    const float* __restrict__ qw,       // [NB][NF]
    const float* __restrict__ mw,       // [NB][NF]
    float4* __restrict__ tableD,
    float* __restrict__ tableM) {
    const int b = blockIdx.x;        // 0..127
    const int lane = threadIdx.x;    // 0..63 == f
    float p0 = probes[b * HD + lane];
    float p1 = probes[b * HD + 64 + lane];
    float ss = wave_allreduce_sum(p0 * p0 + p1 * p1);
    float inv = 1.0f / (sqrtf(ss) + EPSF);
    float pr = p0 * inv, pi = p1 * inv;
    float ang = angles[lane];
    float c = cosf(ang), s = sinf(ang);
    float Pr = pr * c - pi * s;
    float Pi = pr * s + pi * c;
    float x = qw[b * NF + lane];
    // numerically stable softplus
    float sp = (x > 0.0f) ? (x + log1pf(expf(-x))) : log1pf(expf(x));
    tableD[lane * NB + b] = make_float4(-2.0f * Pr, -2.0f * Pi,
                                        Pr * Pr + Pi * Pi + EPSF, -sp);
    tableM[lane * NB + b] = mw[b * NF + lane];
}

// ---------- kernel A2: per-q normalized values ----------
// qvals[q*256 + {0,64,128,192} + f] = {Qr, Qi, Qr^2+Qi^2, Qmag}
__global__ __launch_bounds__(256) void build_qvals_kernel(
    const float* __restrict__ Q,        // [NQ][HD]
    float* __restrict__ qvals) {
    const int q = blockIdx.x * 4 + (threadIdx.x >> 6);
    const int lane = threadIdx.x & 63;  // == f
    float a = Q[q * HD + lane];
    float c2 = Q[q * HD + 64 + lane];
    float ss = wave_allreduce_sum(a * a + c2 * c2);
    float inv = 1.0f / (sqrtf(ss) + EPSF);
    float Qr = a * inv, Qi = c2 * inv;
    float B = Qr * Qr + Qi * Qi;
    float Qm = sqrtf(B + EPSF);
    float* o = qvals + q * 256;
    o[lane] = Qr;
    o[64 + lane] = Qi;
    o[128 + lane] = B;
    o[192 + lane] = Qm;
}

// ---------- kernel B: main ----------
// Wave task: (b-half, 8 q-rows). lane = b within half. f processed in 4
// register-resident chunks of 16 (table in VGPRs -> no LDS traffic in the
// hot loop, which would otherwise be LDS-BW-bound at ~31us).
__global__ __launch_bounds__(256) void main_kernel(
    const float4* __restrict__ tableD,  // [NF][NB]
    const float* __restrict__ tableM,   // [NF][NB]
    const float* __restrict__ qvals,    // [NQ][4][64]
    const float* __restrict__ bias,     // [NB]
    float* __restrict__ out) {          // [NQ][NB]
    const int wave = threadIdx.x >> 6;
    const int lane = threadIdx.x & 63;
    const int task = blockIdx.x * 4 + wave;     // 0..4095
    const int hf = task & 1;                    // b half
    const int qbase = (task >> 1) * 8;          // 8 rows per wave
    const int b = hf * 64 + lane;

    float accs[8];
    #pragma unroll
    for (int i = 0; i < 8; ++i) accs[i] = 0.0f;

    #pragma unroll 1   // keep runtime loop: body is already ~1.2k instrs
    for (int chunk = 0; chunk < 4; ++chunk) {
        // reload table registers for this f-chunk (coalesced: lanes = b)
        float4 td[16];
        float tm[16];
        #pragma unroll
        for (int j = 0; j < 16; ++j) {
            td[j] = tableD[(chunk * 16 + j) * NB + b];
            tm[j] = tableM[(chunk * 16 + j) * NB + b];
        }
        #pragma unroll
        for (int qq = 0; qq < 8; ++qq) {
            const float* qv = qvals + (size_t)(qbase + qq) * 256 + chunk * 16;
            #pragma unroll
            for (int j4 = 0; j4 < 4; ++j4) {
                // uniform-address loads -> single L1 transaction each
                float4 Qr4 = *(const float4*)(qv + j4 * 4);
                float4 Qi4 = *(const float4*)(qv + 64 + j4 * 4);
                float4 Bv4 = *(const float4*)(qv + 128 + j4 * 4);
                float4 Qm4 = *(const float4*)(qv + 192 + j4 * 4);
                const float* Qr = &Qr4.x;
                const float* Qi = &Qi4.x;
                const float* Bv = &Bv4.x;
                const float* Qm = &Qm4.x;
                #pragma unroll
                for (int u = 0; u < 4; ++u) {
                    const int j = j4 * 4 + u;
                    // dist^2 = A + B - 2*Pr*Qr - 2*Pi*Qi  (+eps folded in A)
                    float t = td[j].z + Bv[u];
                    t = fmaf(td[j].y, Qi[u], t);
                    t = fmaf(td[j].x, Qr[u], t);
                    t = fmaxf(t, 0.0f);          // guard fp cancellation
                    float d = __builtin_amdgcn_sqrtf(t);
                    accs[qq] = fmaf(td[j].w, d, accs[qq]);
                    accs[qq] = fmaf(tm[j], Qm[u], accs[qq]);
                }
            }
        }
    }
    float bb = bias[b];
    #pragma unroll
    for (int qq = 0; qq < 8; ++qq)
        out[(size_t)(qbase + qq) * NB + b] = accs[qq] + bb;
}

extern "C" void kernel_launch(void* const* d_in, const int* in_sizes, int n_in,
                              void* d_out, int out_size, void* d_ws, size_t ws_size,
                              hipStream_t stream) {
    const float* Q      = (const float*)d_in[0];   // [16384][128]
    const float* angles = (const float*)d_in[1];   // [64]
    const float* probes = (const float*)d_in[2];   // [128][128]
    const float* qw     = (const float*)d_in[3];   // [128][64]
    const float* mw     = (const float*)d_in[4];   // [128][64]
    const float* bias   = (const float*)d_in[5];   // [128]
    float* out = (float*)d_out;

    // ws layout
    char* ws = (char*)d_ws;
    float4* tableD = (float4*)ws;                         // 64*128*16 = 128 KB
    float*  tableM = (float*)(ws + 64 * NB * sizeof(float4));        // 32 KB
    float*  qvals  = (float*)(ws + 64 * NB * sizeof(float4)
                                 + 64 * NB * sizeof(float));         // 16 MB

    build_table_kernel<<<NB, 64, 0, stream>>>(probes, angles, qw, mw, tableD, tableM);
    build_qvals_kernel<<<NQ / 4, 256, 0, stream>>>(Q, qvals);
    main_kernel<<<(NQ / 8) * 2 / 4, 256, 0, stream>>>(tableD, tableM, qvals, bias, out);
}

// Round 3
// 113.419 us; speedup vs baseline: 1.7012x; 1.7012x over previous
//
#include <hip/hip_runtime.h>

#define NQ 16384
#define NB 128
#define NF 64
#define HD 128
#define EPSF 1e-8f
#define BTILE 8

// ---------- helpers ----------
__device__ __forceinline__ float wave_allreduce_sum(float v) {
    #pragma unroll
    for (int m = 1; m < 64; m <<= 1) v += __shfl_xor(v, m, 64);
    return v;
}

// ---------- kernel A: build (b,f) table ----------
// tableD[f*NB + b] = float4(-2*Pr, -2*Pi, Pr^2+Pi^2+eps, -softplus(qw[b,f]))
// tableM[f*NB + b] = mw[b,f]
__global__ __launch_bounds__(64) void build_table_kernel(
    const float* __restrict__ probes,   // [NB][HD]
    const float* __restrict__ angles,   // [NF]
    const float* __restrict__ qw,       // [NB][NF]
    const float* __restrict__ mw,       // [NB][NF]
    float4* __restrict__ tableD,
    float* __restrict__ tableM) {
    const int b = blockIdx.x;
    const int lane = threadIdx.x;    // == f
    float p0 = probes[b * HD + lane];
    float p1 = probes[b * HD + 64 + lane];
    float ss = wave_allreduce_sum(p0 * p0 + p1 * p1);
    float inv = 1.0f / (sqrtf(ss) + EPSF);
    float pr = p0 * inv, pi = p1 * inv;
    float ang = angles[lane];
    float c = cosf(ang), s = sinf(ang);
    float Pr = pr * c - pi * s;
    float Pi = pr * s + pi * c;
    float x = qw[b * NF + lane];
    float sp = (x > 0.0f) ? (x + log1pf(expf(-x))) : log1pf(expf(x));
    tableD[lane * NB + b] = make_float4(-2.0f * Pr, -2.0f * Pi,
                                        Pr * Pr + Pi * Pi + EPSF, -sp);
    tableM[lane * NB + b] = mw[b * NF + lane];
}

// ---------- kernel A2: per-q normalized values ----------
// qvals[q*NF + f] = float4{Qr, Qi, Qr^2+Qi^2, Qmag}  (coalesced for lane=q reads)
__global__ __launch_bounds__(256) void build_qvals_kernel(
    const float* __restrict__ Q,        // [NQ][HD]
    float4* __restrict__ qvals) {
    const int q = blockIdx.x * 4 + (threadIdx.x >> 6);
    const int lane = threadIdx.x & 63;  // == f
    float a = Q[q * HD + lane];
    float c2 = Q[q * HD + 64 + lane];
    float ss = wave_allreduce_sum(a * a + c2 * c2);
    float inv = 1.0f / (sqrtf(ss) + EPSF);
    float Qr = a * inv, Qi = c2 * inv;
    float B = Qr * Qr + Qi * Qi;
    float Qm = sqrtf(B + EPSF);
    qvals[(size_t)q * NF + lane] = make_float4(Qr, Qi, B, Qm);
}

// ---------- kernel B: main ----------
// lane = q (coalesced qvals loads), BTILE=8 b's per wave from LDS (broadcast
// reads, conflict-free). Block = 4 waves x 64 q, all sharing one btile's
// 10KB LDS table. 1024 blocks -> 4 blocks/CU, 16 waves/CU.
__global__ __launch_bounds__(256, 4) void main_kernel(
    const float4* __restrict__ tableD,  // [NF][NB]
    const float* __restrict__ tableM,   // [NF][NB]
    const float4* __restrict__ qvals,   // [NQ][NF]
    const float* __restrict__ bias,     // [NB]
    float* __restrict__ out) {          // [NQ][NB]
    __shared__ __align__(16) float4 ldsD[NF * BTILE];  // 8 KB
    __shared__ __align__(16) float  ldsM[NF * BTILE];  // 2 KB
    const int bt   = blockIdx.x & 15;   // btile 0..15
    const int qblk = blockIdx.x >> 4;   // 0..63
    const int wave = threadIdx.x >> 6;
    const int lane = threadIdx.x & 63;
    const int q = qblk * 256 + wave * 64 + lane;

    // stage table: 512 float4 + 512 float, 2 each per thread
    #pragma unroll
    for (int i = 0; i < 2; ++i) {
        int idx = threadIdx.x + i * 256;
        int f = idx >> 3, bb = idx & 7;
        ldsD[idx] = tableD[f * NB + bt * BTILE + bb];
        ldsM[idx] = tableM[f * NB + bt * BTILE + bb];
    }
    __syncthreads();

    float acc[BTILE];
    #pragma unroll
    for (int i = 0; i < BTILE; ++i) acc[i] = 0.0f;

    const float4* qp = qvals + (size_t)q * NF;

    #pragma unroll 8
    for (int f = 0; f < NF; ++f) {
        float4 qv = qp[f];                        // coalesced 16B/lane
        float4 tma = *(const float4*)&ldsM[f * 8];
        float4 tmb = *(const float4*)&ldsM[f * 8 + 4];
        const float* tm = &tma.x;  // [0..3] then tmb
        #pragma unroll
        for (int bb = 0; bb < BTILE; ++bb) {
            float4 td = ldsD[f * 8 + bb];         // broadcast, conflict-free
            float t = td.z + qv.z;                // A+eps + B
            t = fmaf(td.y, qv.y, t);              // -2Pi*Qi
            t = fmaf(td.x, qv.x, t);              // -2Pr*Qr
            t = fmaxf(t, 0.0f);                   // fp cancellation guard
            float d = __builtin_amdgcn_sqrtf(t);
            float w = (bb < 4) ? (&tma.x)[bb] : (&tmb.x)[bb - 4];
            acc[bb] = fmaf(td.w, d, acc[bb]);
            acc[bb] = fmaf(w, qv.w, acc[bb]);
        }
    }

    #pragma unroll
    for (int bb = 0; bb < BTILE; ++bb) acc[bb] += bias[bt * BTILE + bb];
    float* op = out + (size_t)q * NB + bt * BTILE;
    *(float4*)op       = make_float4(acc[0], acc[1], acc[2], acc[3]);
    *(float4*)(op + 4) = make_float4(acc[4], acc[5], acc[6], acc[7]);
}

extern "C" void kernel_launch(void* const* d_in, const int* in_sizes, int n_in,
                              void* d_out, int out_size, void* d_ws, size_t ws_size,
                              hipStream_t stream) {
    const float* Q      = (const float*)d_in[0];   // [16384][128]
    const float* angles = (const float*)d_in[1];   // [64]
    const float* probes = (const float*)d_in[2];   // [128][128]
    const float* qw     = (const float*)d_in[3];   // [128][64]
    const float* mw     = (const float*)d_in[4];   // [128][64]
    const float* bias   = (const float*)d_in[5];   // [128]
    float* out = (float*)d_out;

    char* ws = (char*)d_ws;
    float4* tableD = (float4*)ws;                                    // 128 KB
    float*  tableM = (float*)(ws + NF * NB * sizeof(float4));        //  32 KB
    float4* qvals  = (float4*)(ws + NF * NB * sizeof(float4)
                                  + NF * NB * sizeof(float));        //  16 MB

    build_table_kernel<<<NB, 64, 0, stream>>>(probes, angles, qw, mw, tableD, tableM);
    build_qvals_kernel<<<NQ / 4, 256, 0, stream>>>(Q, qvals);
    main_kernel<<<(NQ / 256) * (NB / BTILE), 256, 0, stream>>>(tableD, tableM, qvals, bias, out);
}

// Round 4
// 110.061 us; speedup vs baseline: 1.7531x; 1.0305x over previous
//
#include <hip/hip_runtime.h>

#define NQ 16384
#define NB 128
#define NF 64
#define HD 128
#define EPSF 1e-8f
#define BTILE 8
#define NBT (NB / BTILE)   // 16 btiles

// Per-f table row for one btile: 8 b's worth of
// d = {-2Pr, -2Pi, |P|^2+eps, -softplus(qw)} and m = mw.
// 160 B contiguous -> 2-3 s_load_dwordx16/x8 when address is wave-uniform.
struct FRow {
    float4 d[BTILE];   // 128 B
    float  m[BTILE];   //  32 B
};

// ---------- prep kernel: qvals (blocks 0..2047) + table (blocks 2048..2079) --
// qvals[q*NF + f] = float4{Qr, Qi, Qr^2+Qi^2, Qmag}
__global__ __launch_bounds__(256) void prep_kernel(
    const float* __restrict__ Q,        // [NQ][HD]
    const float* __restrict__ probes,   // [NB][HD]
    const float* __restrict__ angles,   // [NF]
    const float* __restrict__ qw,       // [NB][NF]
    const float* __restrict__ mw,       // [NB][NF]
    float4* __restrict__ qvals,         // [NQ][NF]
    FRow* __restrict__ tab) {           // [NBT][NF]
    if (blockIdx.x < 2048) {
        // ---- qvals: 8 q per block, half-wave (32 lanes) per q ----
        const int q  = blockIdx.x * 8 + (threadIdx.x >> 5);
        const int sl = threadIdx.x & 31;
        const float2* Q2 = (const float2*)Q;
        float2 a = Q2[q * 64 + sl];        // f = 2sl, 2sl+1 (real half)
        float2 c = Q2[q * 64 + 32 + sl];   // imag half
        float ss = a.x * a.x + a.y * a.y + c.x * c.x + c.y * c.y;
        #pragma unroll
        for (int m = 1; m < 32; m <<= 1) ss += __shfl_xor(ss, m);  // stays in half-wave
        float inv = 1.0f / (sqrtf(ss) + EPSF);
        float Qr0 = a.x * inv, Qr1 = a.y * inv;
        float Qi0 = c.x * inv, Qi1 = c.y * inv;
        float B0 = Qr0 * Qr0 + Qi0 * Qi0;
        float B1 = Qr1 * Qr1 + Qi1 * Qi1;
        qvals[(size_t)q * NF + 2 * sl]     = make_float4(Qr0, Qi0, B0, sqrtf(B0 + EPSF));
        qvals[(size_t)q * NF + 2 * sl + 1] = make_float4(Qr1, Qi1, B1, sqrtf(B1 + EPSF));
    } else {
        // ---- table: 1 b per wave, lane = f ----
        const int b    = (blockIdx.x - 2048) * 4 + (threadIdx.x >> 6);
        const int lane = threadIdx.x & 63;   // == f
        float p0 = probes[b * HD + lane];
        float p1 = probes[b * HD + 64 + lane];
        float ss = p0 * p0 + p1 * p1;
        #pragma unroll
        for (int m = 1; m < 64; m <<= 1) ss += __shfl_xor(ss, m);
        float inv = 1.0f / (sqrtf(ss) + EPSF);
        float pr = p0 * inv, pi = p1 * inv;
        float ang = angles[lane];
        float cc = cosf(ang), sn = sinf(ang);
        float Pr = pr * cc - pi * sn;
        float Pi = pr * sn + pi * cc;
        float x = qw[b * NF + lane];
        float sp = (x > 0.0f) ? (x + log1pf(expf(-x))) : log1pf(expf(x));
        FRow* r = &tab[(b >> 3) * NF + lane];
        r->d[b & 7] = make_float4(-2.0f * Pr, -2.0f * Pi, Pr * Pr + Pi * Pi + EPSF, -sp);
        r->m[b & 7] = mw[b * NF + lane];
    }
}

// ---------- main kernel ----------
// lane = q (coalesced qvals b128 loads). Table rows are wave-uniform-address
// -> compiler scalarizes to s_load (SMEM pipe, no VALU/LDS cost); every hot
// VOP then has exactly 1 SGPR operand. No LDS at all.
__global__ __launch_bounds__(256, 4) void main_kernel(
    const FRow* __restrict__ tab,       // [NBT][NF]
    const float4* __restrict__ qvals,   // [NQ][NF]
    const float* __restrict__ bias,     // [NB]
    float* __restrict__ out) {          // [NQ][NB]
    const int bt   = blockIdx.x & (NBT - 1);
    const int qblk = blockIdx.x / NBT;
    const int q = qblk * 256 + (threadIdx.x >> 6) * 64 + (threadIdx.x & 63);

    const FRow* __restrict__ tr = tab + bt * NF;
    const float4* __restrict__ qp = qvals + (size_t)q * NF;

    float acc[BTILE];
    #pragma unroll
    for (int i = 0; i < BTILE; ++i) acc[i] = 0.0f;

    #pragma unroll 4
    for (int f = 0; f < NF; ++f) {
        float4 qv = qp[f];                    // coalesced 16B/lane vector load
        #pragma unroll
        for (int bb = 0; bb < BTILE; ++bb) {
            float4 td = tr[f].d[bb];          // uniform -> SGPRs
            float tm  = tr[f].m[bb];          // uniform -> SGPR
            float t = td.z + qv.z;            // (A+eps) + B
            t = fmaf(td.y, qv.y, t);          // -2Pi*Qi
            t = fmaf(td.x, qv.x, t);          // -2Pr*Qr
            t = fmaxf(t, 0.0f);               // fp-cancellation guard
            float d = __builtin_amdgcn_sqrtf(t);
            acc[bb] = fmaf(td.w, d, acc[bb]);
            acc[bb] = fmaf(tm, qv.w, acc[bb]);
        }
    }

    #pragma unroll
    for (int bb = 0; bb < BTILE; ++bb) acc[bb] += bias[bt * BTILE + bb];
    float* op = out + (size_t)q * NB + bt * BTILE;
    *(float4*)op       = make_float4(acc[0], acc[1], acc[2], acc[3]);
    *(float4*)(op + 4) = make_float4(acc[4], acc[5], acc[6], acc[7]);
}

extern "C" void kernel_launch(void* const* d_in, const int* in_sizes, int n_in,
                              void* d_out, int out_size, void* d_ws, size_t ws_size,
                              hipStream_t stream) {
    const float* Q      = (const float*)d_in[0];   // [16384][128]
    const float* angles = (const float*)d_in[1];   // [64]
    const float* probes = (const float*)d_in[2];   // [128][128]
    const float* qw     = (const float*)d_in[3];   // [128][64]
    const float* mw     = (const float*)d_in[4];   // [128][64]
    const float* bias   = (const float*)d_in[5];   // [128]
    float* out = (float*)d_out;

    char* ws = (char*)d_ws;
    FRow*   tab   = (FRow*)ws;                       // 16*64*160 B = 160 KB
    float4* qvals = (float4*)(ws + NBT * NF * sizeof(FRow));  // 16 MB

    prep_kernel<<<2048 + NB / 4, 256, 0, stream>>>(Q, probes, angles, qw, mw, qvals, tab);
    main_kernel<<<(NQ / 256) * NBT, 256, 0, stream>>>(tab, qvals, bias, out);
}